// Round 13
// baseline (223.210 us; speedup 1.0000x reference)
//
#include <hip/hip_runtime.h>
#include <hip/hip_bf16.h>

#define NE 1600000
#define NN 100000

typedef __attribute__((ext_vector_type(8))) short s16x8;
typedef __attribute__((ext_vector_type(4))) float f32x4;
typedef __attribute__((ext_vector_type(16))) float f32x16;
typedef __attribute__((ext_vector_type(4))) uint u32x4;

__device__ __forceinline__ ushort f2b(float v) {
  union { __hip_bfloat16 h; ushort u; } c; c.h = __float2bfloat16(v); return c.u;
}
// HW packed f32x2 -> bf16x2 (RNE). lo = a, hi = b. Verified on-device (r4-r12).
__device__ __forceinline__ uint cvtpk(float a, float b) {
  uint r;
  asm("v_cvt_pk_bf16_f32 %0, %1, %2" : "=v"(r) : "v"(a), "v"(b));
  return r;
}
__device__ __forceinline__ uint pkrelu(float a, float b) {
  a = fmaxf(a, 0.f); b = fmaxf(b, 0.f);
  return cvtpk(a, b);
}
__device__ __forceinline__ f32x16 mfma32(s16x8 a, s16x8 b, f32x16 c) {
  return __builtin_amdgcn_mfma_f32_32x32x16_bf16(a, b, c, 0, 0, 0);
}
// relu + pack reg-group g (regs 8g..8g+7) of a 32x32 C/D frag -> B-frag word
__device__ __forceinline__ u32x4 packg(const f32x16& a, int g) {
  u32x4 r;
#pragma unroll
  for (int w = 0; w < 4; w++) r[w] = pkrelu(a[8 * g + 2 * w], a[8 * g + 2 * w + 1]);
  return r;
}
// bias C-frag for output tile mt: reg r holds row (r&3)+8*(r>>2)+4*hi
__device__ __forceinline__ f32x16 loadbias(const float* bias, int mt, int hi) {
  f32x16 b;
#pragma unroll
  for (int q4 = 0; q4 < 4; q4++) {
    f32x4 v = *(const f32x4*)(bias + mt * 32 + q4 * 8 + hi * 4);
#pragma unroll
    for (int i = 0; i < 4; i++) b[q4 * 4 + i] = v[i];
  }
  return b;
}

// ---- prep: weights -> 32x32x16 MFMA A-fragment order (bf16).
// A-frag (tile mt): lane l holds Wjax[k][mt*32+(l&31)] for k = (l>>5)*8 + j.
// PRODUCER (L0) k-map: edge net: k0-4 sender, k8-12 receiver, k13 bias;
// node net: k0-4 node, k8-9 pooled, k10 bias. (All within one K=16 step.)
// CONSUMER (W1,W2,W3): input-channel index = swap bits 2<->3 of k, so the
// producer's packed C/D regs [8g..8g+7] are directly the next B-fragment.
__global__ void prep_weights(const float* s0, const float* s1, const float* s2, const float* s3,
                             const float* s4, const float* s5, const float* s6, const float* s7,
                             const float* bm0, const float* bu0, ushort* dst) {
  const int NFRAG[8] = {4, 32, 32, 8, 4, 32, 32, 8};
  const int offs[8]  = {0, 2048, 18432, 34816, 38912, 40960, 57344, 73728};
  const float* srcs[8] = {s0, s1, s2, s3, s4, s5, s6, s7};
  int b = blockIdx.x;
  int cnt = NFRAG[b] * 512;
  const float* src = srcs[b];
  bool isProducer = (b == 0 || b == 4);
  bool isHead = (b == 3 || b == 7);
  int F1 = (b < 4) ? 5 : 2;
  int kbias = (b < 4) ? 13 : 10;
  const float* bp = (b < 4) ? bm0 : bu0;
  ushort* d = dst + offs[b];
  for (int idx = threadIdx.x; idx < cnt; idx += blockDim.x) {
    int f = idx >> 9, r = idx & 511, lane = r >> 3, j = r & 7;
    int hi = lane >> 5, m = lane & 31;
    float v = 0.f;
    if (isProducer) {
      int ch = f * 32 + m;
      int k = hi * 8 + j;
      int row = -1;
      if (k < 5) row = k;
      else if (k >= 8 && k < 8 + F1) row = k - 3;
      if (row >= 0) v = src[row * 128 + ch];
      else if (k == kbias) v = bp[ch];
    } else {
      int s = isHead ? f : (f >> 2);
      int k = s * 16 + hi * 8 + j;
      int c = (k & ~12) | ((k & 4) << 1) | ((k & 8) >> 1);   // swap bits 2,3
      if (isHead) v = (m < 2) ? src[c * 2 + m] : 0.f;
      else {
        int ch = (f & 3) * 32 + m;
        v = src[c * 128 + ch];
      }
    }
    d[idx] = f2b(v);
  }
}

// ---- main: wave-specialized pipeline (front L0+L1 / back L2+head), pair-local
// LDS flag sync (r12, verified), 32x32x16 MFMA: 80 MFMA per 32-edge batch.
template <int MODE>
__global__ __launch_bounds__(512, 2)
void gnn_kernel(const float* __restrict__ nodes,
                const int* __restrict__ eidx,
                float* __restrict__ pooled,
                const ushort* __restrict__ wsrc,
                const float* __restrict__ b1g, const float* __restrict__ b2g,
                const float* __restrict__ b3g,
                float* __restrict__ out) {
  __shared__ __align__(16) char hand[65536];     // 4 pairs x 2 bufs x 8192 B
  __shared__ __align__(16) float bias1[128];
  __shared__ __align__(16) float bias2[128];
  __shared__ __align__(16) float bias3[16];
  __shared__ uint flags[64];                     // prod[pr]=flags[pr*8], cons=flags[32+pr*8]
  if (threadIdx.x < 128) {
    bias1[threadIdx.x] = b1g[threadIdx.x];
    bias2[threadIdx.x] = b2g[threadIdx.x];
  }
  if (threadIdx.x < 16) bias3[threadIdx.x] = (threadIdx.x < 2) ? b3g[threadIdx.x] : 0.f;
  if (threadIdx.x < 64) flags[threadIdx.x] = 0u;

  const int wv = threadIdx.x >> 6;
  const int l = threadIdx.x & 63;
  const int hi = l >> 5;
  const int e32 = l & 31;
  const bool front = (wv < 4);
  const int pr = wv & 3;
  char* hbase = hand + pr * 16384;
  volatile uint* prodv = &flags[pr * 8];
  volatile uint* consv = &flags[32 + pr * 8];

  // unioned weights: front: WA[0..3]=W0 tiles, WB[s][mt]=W1; back: WA[s]=W3, WB=W2
  s16x8 WA[8];
  s16x8 WB[8][4];
  if (front) {
#pragma unroll
    for (int mt = 0; mt < 4; mt++)
      WA[mt] = *(const s16x8*)(wsrc + ((mt * 64 + l) * 8));
#pragma unroll
    for (int s = 0; s < 8; s++)
#pragma unroll
      for (int mt = 0; mt < 4; mt++)
        WB[s][mt] = *(const s16x8*)(wsrc + 2048 + (((s * 4 + mt) * 64 + l) * 8));
  } else {
#pragma unroll
    for (int s = 0; s < 8; s++)
      WA[s] = *(const s16x8*)(wsrc + 34816 + ((s * 64 + l) * 8));
#pragma unroll
    for (int s = 0; s < 8; s++)
#pragma unroll
      for (int mt = 0; mt < 4; mt++)
        WB[s][mt] = *(const s16x8*)(wsrc + 18432 + (((s * 4 + mt) * 64 + l) * 8));
  }
  __syncthreads();   // weights/bias/flags visible

  const int np = gridDim.x << 2;
  const int gp = (blockIdx.x << 2) + pr;
  const int NB = (MODE == 0) ? (NE / 32) : (NN / 32);
  const f32x16 z16 = {0.f, 0.f, 0.f, 0.f, 0.f, 0.f, 0.f, 0.f,
                      0.f, 0.f, 0.f, 0.f, 0.f, 0.f, 0.f, 0.f};

  if (front) {
    // gather: lane = (edge e32, half hi). hi0 = sender/node, hi1 = receiver/pooled.
    float g0 = 0, g1 = 0, g2 = 0, g3 = 0, g4 = 0;
    auto PREF = [&](int bb) {
      if (bb < NB) {
        int e = (bb << 5) + e32;
        if (MODE == 0) {
          int idx = eidx[hi * NE + e];
          const float* np_ = nodes + idx * 5;
          g0 = np_[0]; g1 = np_[1]; g2 = np_[2]; g3 = np_[3]; g4 = np_[4];
        } else {
          if (hi == 0) {
            const float* np_ = nodes + e * 5;
            g0 = np_[0]; g1 = np_[1]; g2 = np_[2]; g3 = np_[3]; g4 = np_[4];
          } else {
            float2 pl = *(const float2*)&pooled[e * 2];
            g0 = pl.x; g1 = pl.y;
          }
        }
      }
    };
    PREF(gp);

    int t = 0;
#pragma unroll 1
    for (int b = gp; b < NB; b += np, ++t) {
      // build the single L0 B-fragment (K=16 covers all input slots)
      s16x8 xf;
      {
        u32x4 f = {0u, 0u, 0u, 0u};
        if (MODE == 0) {
          f[0] = cvtpk(g0, g1); f[1] = cvtpk(g2, g3);
          f[2] = cvtpk(g4, hi ? 1.0f : 0.0f);          // bias rides k13 (hi=1,j=5)
        } else {
          if (hi == 0) { f[0] = cvtpk(g0, g1); f[1] = cvtpk(g2, g3); f[2] = cvtpk(g4, 0.f); }
          else         { f[0] = cvtpk(g0, g1); f[1] = cvtpk(1.0f, 0.f); }  // bias k10
        }
        xf = __builtin_bit_cast(s16x8, f);
      }
      PREF(b + np);

      // L0: 4 MFMA (bias folded into W0)
      u32x4 phA[4][2];
#pragma unroll
      for (int mt = 0; mt < 4; mt++) {
        f32x16 a = mfma32(WA[mt], xf, z16);
        phA[mt][0] = packg(a, 0);
        phA[mt][1] = packg(a, 1);
      }
      // wait until back consumed buf[t&1] (from iter t-2)
      if (t >= 2) {
        while (*consv < (uint)(t - 1)) __builtin_amdgcn_s_sleep(1);
        __builtin_amdgcn_sched_barrier(0);
      }
      // L1: 32 MFMA, bias via C, write H2 to LDS buf[t&1]
      char* wb = hbase + (t & 1) * 8192;
#pragma unroll
      for (int mt = 0; mt < 4; mt++) {
        f32x16 a = mfma32(WB[0][mt], __builtin_bit_cast(s16x8, phA[0][0]),
                          loadbias(bias1, mt, hi));
#pragma unroll
        for (int s = 1; s < 8; s++)
          a = mfma32(WB[s][mt], __builtin_bit_cast(s16x8, phA[s >> 1][s & 1]), a);
        u32x4 h0 = packg(a, 0), h1 = packg(a, 1);
        *(u32x4*)(wb + ((mt << 1) + 0) * 1024 + l * 16) = h0;
        *(u32x4*)(wb + ((mt << 1) + 1) * 1024 + l * 16) = h1;
      }
      __builtin_amdgcn_sched_barrier(0);
      if (l == 0) *prodv = (uint)(t + 1);
      __builtin_amdgcn_sched_barrier(0);
    }
  } else {
    int bc = 0;
#pragma unroll 1
    for (int b = gp; b < NB; b += np, ++bc) {
      const int rbase = b << 5;
      int rc = 0;
      if (MODE == 0 && hi == 0) rc = eidx[NE + rbase + e32];
      // wait for front's buf[bc&1]
      while (*prodv < (uint)(bc + 1)) __builtin_amdgcn_s_sleep(1);
      __builtin_amdgcn_sched_barrier(0);
      const char* rb = hbase + (bc & 1) * 8192;
      u32x4 pin[8];
#pragma unroll
      for (int s = 0; s < 8; s++)
        pin[s] = *(const u32x4*)(rb + s * 1024 + l * 16);
      __builtin_amdgcn_sched_barrier(0);
      if (l == 0) *consv = (uint)(bc + 1);
      __builtin_amdgcn_sched_barrier(0);
      // L2: 32 MFMA, bias via C
      u32x4 phC[4][2];
#pragma unroll
      for (int mt = 0; mt < 4; mt++) {
        f32x16 a = mfma32(WB[0][mt], __builtin_bit_cast(s16x8, pin[0]),
                          loadbias(bias2, mt, hi));
#pragma unroll
        for (int s = 1; s < 8; s++)
          a = mfma32(WB[s][mt], __builtin_bit_cast(s16x8, pin[s]), a);
        phC[mt][0] = packg(a, 0);
        phC[mt][1] = packg(a, 1);
      }
      // head: 8 MFMA, one tile (rows 0,1 valid -> hi==0 regs 0,1)
      f32x16 a = mfma32(WA[0], __builtin_bit_cast(s16x8, phC[0][0]), z16);
#pragma unroll
      for (int s = 1; s < 8; s++)
        a = mfma32(WA[s], __builtin_bit_cast(s16x8, phC[s >> 1][s & 1]), a);

      int e = rbase + e32;
      if (hi == 0) {
        float mv0 = a[0] + bias3[0], mv1 = a[1] + bias3[1];
        if (MODE == 0) {
          unsafeAtomicAdd(&pooled[rc * 2], mv0);
          unsafeAtomicAdd(&pooled[rc * 2 + 1], mv1);
        } else {
          out[e * 5 + 2] = nodes[e * 5 + 2] + mv0;
          out[e * 5 + 3] = nodes[e * 5 + 3] + mv1;
        }
      } else if (MODE == 1) {
        out[e * 5 + 0] = nodes[e * 5 + 0];
        out[e * 5 + 1] = nodes[e * 5 + 1];
        out[e * 5 + 4] = nodes[e * 5 + 4];
      }
    }
  }
}

extern "C" void kernel_launch(void* const* d_in, const int* in_sizes, int n_in,
                              void* d_out, int out_size, void* d_ws, size_t ws_size,
                              hipStream_t stream) {
  const float* nodes = (const float*)d_in[0];
  const int* eidx = (const int*)d_in[1];
  const float* Wm0 = (const float*)d_in[2];  const float* bm0 = (const float*)d_in[3];
  const float* Wm1 = (const float*)d_in[4];  const float* bm1 = (const float*)d_in[5];
  const float* Wm2 = (const float*)d_in[6];  const float* bm2 = (const float*)d_in[7];
  const float* Wm3 = (const float*)d_in[8];  const float* bm3 = (const float*)d_in[9];
  const float* Wu0 = (const float*)d_in[10]; const float* bu0 = (const float*)d_in[11];
  const float* Wu1 = (const float*)d_in[12]; const float* bu1 = (const float*)d_in[13];
  const float* Wu2 = (const float*)d_in[14]; const float* bu2 = (const float*)d_in[15];
  const float* Wu3 = (const float*)d_in[16]; const float* bu3 = (const float*)d_in[17];

  float* pooled = (float*)d_ws;                     // NN*2 f32 = 800000 B
  ushort* wbuf = (ushort*)((char*)d_ws + 800000);   // 2*38912 prearranged bf16

  hipMemsetAsync(pooled, 0, NN * 2 * sizeof(float), stream);
  prep_weights<<<8, 256, 0, stream>>>(Wm0, Wm1, Wm2, Wm3, Wu0, Wu1, Wu2, Wu3,
                                      bm0, bu0, wbuf);

  gnn_kernel<0><<<256, 512, 0, stream>>>(nodes, eidx, pooled, wbuf,
                                         bm1, bm2, bm3, nullptr);
  gnn_kernel<1><<<256, 512, 0, stream>>>(nodes, nullptr, pooled, wbuf + 38912,
                                         bu1, bu2, bu3, (float*)d_out);
}

// Round 14
// 170.429 us; speedup vs baseline: 1.3097x; 1.3097x over previous
//
#include <hip/hip_runtime.h>
#include <hip/hip_bf16.h>

#define NE 1600000
#define NN 100000
#define PSCALE 131072.0f   // 2^17 fixed-point scale for pooled accumulation

typedef __attribute__((ext_vector_type(8))) short s16x8;
typedef __attribute__((ext_vector_type(4))) float f32x4;
typedef __attribute__((ext_vector_type(16))) float f32x16;
typedef __attribute__((ext_vector_type(4))) uint u32x4;

__device__ __forceinline__ ushort f2b(float v) {
  union { __hip_bfloat16 h; ushort u; } c; c.h = __float2bfloat16(v); return c.u;
}
// HW packed f32x2 -> bf16x2 (RNE). lo = a, hi = b. Verified on-device (r4-r13).
__device__ __forceinline__ uint cvtpk(float a, float b) {
  uint r;
  asm("v_cvt_pk_bf16_f32 %0, %1, %2" : "=v"(r) : "v"(a), "v"(b));
  return r;
}
__device__ __forceinline__ uint pkrelu(float a, float b) {
  a = fmaxf(a, 0.f); b = fmaxf(b, 0.f);
  return cvtpk(a, b);
}
__device__ __forceinline__ f32x16 mfma32(s16x8 a, s16x8 b, f32x16 c) {
  return __builtin_amdgcn_mfma_f32_32x32x16_bf16(a, b, c, 0, 0, 0);
}
// relu + pack reg-group g (regs 8g..8g+7) of a 32x32 C/D frag -> B-frag word
__device__ __forceinline__ u32x4 packg(const f32x16& a, int g) {
  u32x4 r;
#pragma unroll
  for (int w = 0; w < 4; w++) r[w] = pkrelu(a[8 * g + 2 * w], a[8 * g + 2 * w + 1]);
  return r;
}
// bias C-frag for output tile mt: reg r holds row (r&3)+8*(r>>2)+4*hi
__device__ __forceinline__ f32x16 loadbias(const float* bias, int mt, int hi) {
  f32x16 b;
#pragma unroll
  for (int q4 = 0; q4 < 4; q4++) {
    f32x4 v = *(const f32x4*)(bias + mt * 32 + q4 * 8 + hi * 4);
#pragma unroll
    for (int i = 0; i < 4; i++) b[q4 * 4 + i] = v[i];
  }
  return b;
}

// ---- prep: identical to r13 (verified). Weights -> 32x32x16 A-fragment order.
__global__ void prep_weights(const float* s0, const float* s1, const float* s2, const float* s3,
                             const float* s4, const float* s5, const float* s6, const float* s7,
                             const float* bm0, const float* bu0, ushort* dst) {
  const int NFRAG[8] = {4, 32, 32, 8, 4, 32, 32, 8};
  const int offs[8]  = {0, 2048, 18432, 34816, 38912, 40960, 57344, 73728};
  const float* srcs[8] = {s0, s1, s2, s3, s4, s5, s6, s7};
  int b = blockIdx.x;
  int cnt = NFRAG[b] * 512;
  const float* src = srcs[b];
  bool isProducer = (b == 0 || b == 4);
  bool isHead = (b == 3 || b == 7);
  int F1 = (b < 4) ? 5 : 2;
  int kbias = (b < 4) ? 13 : 10;
  const float* bp = (b < 4) ? bm0 : bu0;
  ushort* d = dst + offs[b];
  for (int idx = threadIdx.x; idx < cnt; idx += blockDim.x) {
    int f = idx >> 9, r = idx & 511, lane = r >> 3, j = r & 7;
    int hi = lane >> 5, m = lane & 31;
    float v = 0.f;
    if (isProducer) {
      int ch = f * 32 + m;
      int k = hi * 8 + j;
      int row = -1;
      if (k < 5) row = k;
      else if (k >= 8 && k < 8 + F1) row = k - 3;
      if (row >= 0) v = src[row * 128 + ch];
      else if (k == kbias) v = bp[ch];
    } else {
      int s = isHead ? f : (f >> 2);
      int k = s * 16 + hi * 8 + j;
      int c = (k & ~12) | ((k & 4) << 1) | ((k & 8) >> 1);   // swap bits 2,3
      if (isHead) v = (m < 2) ? src[c * 2 + m] : 0.f;
      else {
        int ch = (f & 3) * 32 + m;
        v = src[c * 128 + ch];
      }
    }
    d[idx] = f2b(v);
  }
}

// ---- main: r13 structure (verified), single change: pooled scatter uses ONE
// u64 fixed-point atomic per edge (exact int64 math) instead of two f32 atomics.
// pooled[n] accumulates ((i64)round(y*2^17)<<32) + (i64)round(x*2^17).
template <int MODE>
__global__ __launch_bounds__(512, 2)
void gnn_kernel(const float* __restrict__ nodes,
                const int* __restrict__ eidx,
                unsigned long long* __restrict__ pooled,
                const ushort* __restrict__ wsrc,
                const float* __restrict__ b1g, const float* __restrict__ b2g,
                const float* __restrict__ b3g,
                float* __restrict__ out) {
  __shared__ __align__(16) char hand[65536];     // 4 pairs x 2 bufs x 8192 B
  __shared__ __align__(16) float bias1[128];
  __shared__ __align__(16) float bias2[128];
  __shared__ __align__(16) float bias3[16];
  __shared__ uint flags[64];                     // prod[pr]=flags[pr*8], cons=flags[32+pr*8]
  if (threadIdx.x < 128) {
    bias1[threadIdx.x] = b1g[threadIdx.x];
    bias2[threadIdx.x] = b2g[threadIdx.x];
  }
  if (threadIdx.x < 16) bias3[threadIdx.x] = (threadIdx.x < 2) ? b3g[threadIdx.x] : 0.f;
  if (threadIdx.x < 64) flags[threadIdx.x] = 0u;

  const int wv = threadIdx.x >> 6;
  const int l = threadIdx.x & 63;
  const int hi = l >> 5;
  const int e32 = l & 31;
  const bool front = (wv < 4);
  const int pr = wv & 3;
  char* hbase = hand + pr * 16384;
  volatile uint* prodv = &flags[pr * 8];
  volatile uint* consv = &flags[32 + pr * 8];

  // unioned weights: front: WA[0..3]=W0 tiles, WB[s][mt]=W1; back: WA[s]=W3, WB=W2
  s16x8 WA[8];
  s16x8 WB[8][4];
  if (front) {
#pragma unroll
    for (int mt = 0; mt < 4; mt++)
      WA[mt] = *(const s16x8*)(wsrc + ((mt * 64 + l) * 8));
#pragma unroll
    for (int s = 0; s < 8; s++)
#pragma unroll
      for (int mt = 0; mt < 4; mt++)
        WB[s][mt] = *(const s16x8*)(wsrc + 2048 + (((s * 4 + mt) * 64 + l) * 8));
  } else {
#pragma unroll
    for (int s = 0; s < 8; s++)
      WA[s] = *(const s16x8*)(wsrc + 34816 + ((s * 64 + l) * 8));
#pragma unroll
    for (int s = 0; s < 8; s++)
#pragma unroll
      for (int mt = 0; mt < 4; mt++)
        WB[s][mt] = *(const s16x8*)(wsrc + 18432 + (((s * 4 + mt) * 64 + l) * 8));
  }
  __syncthreads();   // weights/bias/flags visible

  const int np = gridDim.x << 2;
  const int gp = (blockIdx.x << 2) + pr;
  const int NB = (MODE == 0) ? (NE / 32) : (NN / 32);
  const f32x16 z16 = {0.f, 0.f, 0.f, 0.f, 0.f, 0.f, 0.f, 0.f,
                      0.f, 0.f, 0.f, 0.f, 0.f, 0.f, 0.f, 0.f};

  if (front) {
    // gather: lane = (edge e32, half hi). hi0 = sender/node, hi1 = receiver/pooled.
    float g0 = 0, g1 = 0, g2 = 0, g3 = 0, g4 = 0;
    auto PREF = [&](int bb) {
      if (bb < NB) {
        int e = (bb << 5) + e32;
        if (MODE == 0) {
          int idx = eidx[hi * NE + e];
          const float* np_ = nodes + idx * 5;
          g0 = np_[0]; g1 = np_[1]; g2 = np_[2]; g3 = np_[3]; g4 = np_[4];
        } else {
          if (hi == 0) {
            const float* np_ = nodes + e * 5;
            g0 = np_[0]; g1 = np_[1]; g2 = np_[2]; g3 = np_[3]; g4 = np_[4];
          } else {
            unsigned long long pl = pooled[e];
            int x32 = (int)(uint)pl;
            int y32 = (int)(pl >> 32) + (x32 < 0 ? 1 : 0);
            g0 = (float)x32 * (1.f / PSCALE);
            g1 = (float)y32 * (1.f / PSCALE);
          }
        }
      }
    };
    PREF(gp);

    int t = 0;
#pragma unroll 1
    for (int b = gp; b < NB; b += np, ++t) {
      // build the single L0 B-fragment (K=16 covers all input slots)
      s16x8 xf;
      {
        u32x4 f = {0u, 0u, 0u, 0u};
        if (MODE == 0) {
          f[0] = cvtpk(g0, g1); f[1] = cvtpk(g2, g3);
          f[2] = cvtpk(g4, hi ? 1.0f : 0.0f);          // bias rides k13 (hi=1,j=5)
        } else {
          if (hi == 0) { f[0] = cvtpk(g0, g1); f[1] = cvtpk(g2, g3); f[2] = cvtpk(g4, 0.f); }
          else         { f[0] = cvtpk(g0, g1); f[1] = cvtpk(1.0f, 0.f); }  // bias k10
        }
        xf = __builtin_bit_cast(s16x8, f);
      }
      PREF(b + np);

      // L0: 4 MFMA (bias folded into W0)
      u32x4 phA[4][2];
#pragma unroll
      for (int mt = 0; mt < 4; mt++) {
        f32x16 a = mfma32(WA[mt], xf, z16);
        phA[mt][0] = packg(a, 0);
        phA[mt][1] = packg(a, 1);
      }
      // wait until back consumed buf[t&1] (from iter t-2)
      if (t >= 2) {
        while (*consv < (uint)(t - 1)) __builtin_amdgcn_s_sleep(1);
        __builtin_amdgcn_sched_barrier(0);
      }
      // L1: 32 MFMA, bias via C, write H2 to LDS buf[t&1]
      char* wb = hbase + (t & 1) * 8192;
#pragma unroll
      for (int mt = 0; mt < 4; mt++) {
        f32x16 a = mfma32(WB[0][mt], __builtin_bit_cast(s16x8, phA[0][0]),
                          loadbias(bias1, mt, hi));
#pragma unroll
        for (int s = 1; s < 8; s++)
          a = mfma32(WB[s][mt], __builtin_bit_cast(s16x8, phA[s >> 1][s & 1]), a);
        u32x4 h0 = packg(a, 0), h1 = packg(a, 1);
        *(u32x4*)(wb + ((mt << 1) + 0) * 1024 + l * 16) = h0;
        *(u32x4*)(wb + ((mt << 1) + 1) * 1024 + l * 16) = h1;
      }
      __builtin_amdgcn_sched_barrier(0);
      if (l == 0) *prodv = (uint)(t + 1);
      __builtin_amdgcn_sched_barrier(0);
    }
  } else {
    int bc = 0;
#pragma unroll 1
    for (int b = gp; b < NB; b += np, ++bc) {
      const int rbase = b << 5;
      int rc = 0;
      if (MODE == 0 && hi == 0) rc = eidx[NE + rbase + e32];
      // wait for front's buf[bc&1]
      while (*prodv < (uint)(bc + 1)) __builtin_amdgcn_s_sleep(1);
      __builtin_amdgcn_sched_barrier(0);
      const char* rb = hbase + (bc & 1) * 8192;
      u32x4 pin[8];
#pragma unroll
      for (int s = 0; s < 8; s++)
        pin[s] = *(const u32x4*)(rb + s * 1024 + l * 16);
      __builtin_amdgcn_sched_barrier(0);
      if (l == 0) *consv = (uint)(bc + 1);
      __builtin_amdgcn_sched_barrier(0);
      // L2: 32 MFMA, bias via C
      u32x4 phC[4][2];
#pragma unroll
      for (int mt = 0; mt < 4; mt++) {
        f32x16 a = mfma32(WB[0][mt], __builtin_bit_cast(s16x8, pin[0]),
                          loadbias(bias2, mt, hi));
#pragma unroll
        for (int s = 1; s < 8; s++)
          a = mfma32(WB[s][mt], __builtin_bit_cast(s16x8, pin[s]), a);
        phC[mt][0] = packg(a, 0);
        phC[mt][1] = packg(a, 1);
      }
      // head: 8 MFMA, one tile (rows 0,1 valid -> hi==0 regs 0,1)
      f32x16 a = mfma32(WA[0], __builtin_bit_cast(s16x8, phC[0][0]), z16);
#pragma unroll
      for (int s = 1; s < 8; s++)
        a = mfma32(WA[s], __builtin_bit_cast(s16x8, phC[s >> 1][s & 1]), a);

      int e = rbase + e32;
      if (hi == 0) {
        float mv0 = a[0] + bias3[0], mv1 = a[1] + bias3[1];
        if (MODE == 0) {
          // ONE exact fixed-point u64 atomic per edge (halves atomic count)
          int ix = (int)rintf(mv0 * PSCALE);
          int iy = (int)rintf(mv1 * PSCALE);
          long long ad = (((long long)iy) << 32) + (long long)ix;
          atomicAdd(&pooled[rc], (unsigned long long)ad);
        } else {
          out[e * 5 + 2] = nodes[e * 5 + 2] + mv0;
          out[e * 5 + 3] = nodes[e * 5 + 3] + mv1;
        }
      } else if (MODE == 1) {
        out[e * 5 + 0] = nodes[e * 5 + 0];
        out[e * 5 + 1] = nodes[e * 5 + 1];
        out[e * 5 + 4] = nodes[e * 5 + 4];
      }
    }
  }
}

extern "C" void kernel_launch(void* const* d_in, const int* in_sizes, int n_in,
                              void* d_out, int out_size, void* d_ws, size_t ws_size,
                              hipStream_t stream) {
  const float* nodes = (const float*)d_in[0];
  const int* eidx = (const int*)d_in[1];
  const float* Wm0 = (const float*)d_in[2];  const float* bm0 = (const float*)d_in[3];
  const float* Wm1 = (const float*)d_in[4];  const float* bm1 = (const float*)d_in[5];
  const float* Wm2 = (const float*)d_in[6];  const float* bm2 = (const float*)d_in[7];
  const float* Wm3 = (const float*)d_in[8];  const float* bm3 = (const float*)d_in[9];
  const float* Wu0 = (const float*)d_in[10]; const float* bu0 = (const float*)d_in[11];
  const float* Wu1 = (const float*)d_in[12]; const float* bu1 = (const float*)d_in[13];
  const float* Wu2 = (const float*)d_in[14]; const float* bu2 = (const float*)d_in[15];
  const float* Wu3 = (const float*)d_in[16]; const float* bu3 = (const float*)d_in[17];

  unsigned long long* pooled = (unsigned long long*)d_ws;  // NN u64 = 800000 B
  ushort* wbuf = (ushort*)((char*)d_ws + 800000);          // prearranged bf16 frags

  hipMemsetAsync(pooled, 0, NN * 8, stream);
  prep_weights<<<8, 256, 0, stream>>>(Wm0, Wm1, Wm2, Wm3, Wu0, Wu1, Wu2, Wu3,
                                      bm0, bu0, wbuf);

  gnn_kernel<0><<<256, 512, 0, stream>>>(nodes, eidx, pooled, wbuf,
                                         bm1, bm2, bm3, nullptr);
  gnn_kernel<1><<<256, 512, 0, stream>>>(nodes, nullptr, pooled, wbuf + 38912,
                                         bu1, bu2, bu3, (float*)d_out);
}

// Round 15
// 165.903 us; speedup vs baseline: 1.3454x; 1.0273x over previous
//
#include <hip/hip_runtime.h>
#include <hip/hip_bf16.h>

#define NE 1600000
#define NN 100000
#define PSCALE 131072.0f   // 2^17 fixed-point scale for pooled accumulation

typedef __attribute__((ext_vector_type(8))) short s16x8;
typedef __attribute__((ext_vector_type(4))) float f32x4;
typedef __attribute__((ext_vector_type(16))) float f32x16;
typedef __attribute__((ext_vector_type(4))) int i32x4;
typedef __attribute__((ext_vector_type(4))) uint u32x4;

__device__ __forceinline__ ushort f2b(float v) {
  union { __hip_bfloat16 h; ushort u; } c; c.h = __float2bfloat16(v); return c.u;
}
// HW packed f32x2 -> bf16x2 (RNE). lo = a, hi = b. Verified on-device (r4-r14).
__device__ __forceinline__ uint cvtpk(float a, float b) {
  uint r;
  asm("v_cvt_pk_bf16_f32 %0, %1, %2" : "=v"(r) : "v"(a), "v"(b));
  return r;
}
__device__ __forceinline__ uint pkrelu(float a, float b) {
  a = fmaxf(a, 0.f); b = fmaxf(b, 0.f);
  return cvtpk(a, b);
}
__device__ __forceinline__ f32x16 mfma32(s16x8 a, s16x8 b, f32x16 c) {
  return __builtin_amdgcn_mfma_f32_32x32x16_bf16(a, b, c, 0, 0, 0);
}
// relu + pack reg-group g (regs 8g..8g+7) of a 32x32 C/D frag -> B-frag word
__device__ __forceinline__ u32x4 packg(const f32x16& a, int g) {
  u32x4 r;
#pragma unroll
  for (int w = 0; w < 4; w++) r[w] = pkrelu(a[8 * g + 2 * w], a[8 * g + 2 * w + 1]);
  return r;
}
// bias C-frag for output tile mt: reg r holds row (r&3)+8*(r>>2)+4*hi
__device__ __forceinline__ f32x16 loadbias(const float* bias, int mt, int hi) {
  f32x16 b;
#pragma unroll
  for (int q4 = 0; q4 < 4; q4++) {
    f32x4 v = *(const f32x4*)(bias + mt * 32 + q4 * 8 + hi * 4);
#pragma unroll
    for (int i = 0; i < 4; i++) b[q4 * 4 + i] = v[i];
  }
  return b;
}

// ---- prep: identical to r13/r14 (verified). Weights -> 32x32x16 A-frag order.
__global__ void prep_weights(const float* s0, const float* s1, const float* s2, const float* s3,
                             const float* s4, const float* s5, const float* s6, const float* s7,
                             const float* bm0, const float* bu0, ushort* dst) {
  const int NFRAG[8] = {4, 32, 32, 8, 4, 32, 32, 8};
  const int offs[8]  = {0, 2048, 18432, 34816, 38912, 40960, 57344, 73728};
  const float* srcs[8] = {s0, s1, s2, s3, s4, s5, s6, s7};
  int b = blockIdx.x;
  int cnt = NFRAG[b] * 512;
  const float* src = srcs[b];
  bool isProducer = (b == 0 || b == 4);
  bool isHead = (b == 3 || b == 7);
  int F1 = (b < 4) ? 5 : 2;
  int kbias = (b < 4) ? 13 : 10;
  const float* bp = (b < 4) ? bm0 : bu0;
  ushort* d = dst + offs[b];
  for (int idx = threadIdx.x; idx < cnt; idx += blockDim.x) {
    int f = idx >> 9, r = idx & 511, lane = r >> 3, j = r & 7;
    int hi = lane >> 5, m = lane & 31;
    float v = 0.f;
    if (isProducer) {
      int ch = f * 32 + m;
      int k = hi * 8 + j;
      int row = -1;
      if (k < 5) row = k;
      else if (k >= 8 && k < 8 + F1) row = k - 3;
      if (row >= 0) v = src[row * 128 + ch];
      else if (k == kbias) v = bp[ch];
    } else {
      int s = isHead ? f : (f >> 2);
      int k = s * 16 + hi * 8 + j;
      int c = (k & ~12) | ((k & 4) << 1) | ((k & 8) >> 1);   // swap bits 2,3
      if (isHead) v = (m < 2) ? src[c * 2 + m] : 0.f;
      else {
        int ch = (f & 3) * 32 + m;
        v = src[c * 128 + ch];
      }
    }
    d[idx] = f2b(v);
  }
}

// ---- main: UNIFORM waves, weights streamed from LDS through an explicit
// depth-8 register double-buffer (next tile's 8 ds_read_b128 issued before the
// current tile's 8 MFMAs -> ~120cy LDS latency hidden under 256cy of MFMA).
// 32x32x16 MFMA (r13), u64 fixed-point atomic (r14). No barriers in main loop.
template <int MODE>
__global__ __launch_bounds__(512, 2)
void gnn_kernel(const float* __restrict__ nodes,
                const int* __restrict__ eidx,
                unsigned long long* __restrict__ pooled,
                const ushort* __restrict__ wsrc,
                const float* __restrict__ b1g, const float* __restrict__ b2g,
                const float* __restrict__ b3g,
                float* __restrict__ out) {
  __shared__ __align__(16) ushort wlds[38912];   // 76 frags x 1KB
  __shared__ __align__(16) float bias1[128];
  __shared__ __align__(16) float bias2[128];
  __shared__ __align__(16) float bias3[16];
  {
    i32x4* dw = (i32x4*)wlds;
    const i32x4* sw = (const i32x4*)wsrc;
    for (int i = threadIdx.x; i < 4864; i += 512) dw[i] = sw[i];
    if (threadIdx.x < 128) {
      bias1[threadIdx.x] = b1g[threadIdx.x];
      bias2[threadIdx.x] = b2g[threadIdx.x];
    }
    if (threadIdx.x < 16) bias3[threadIdx.x] = (threadIdx.x < 2) ? b3g[threadIdx.x] : 0.f;
  }
  __syncthreads();

  const int wv = threadIdx.x >> 6;
  const int l = threadIdx.x & 63;
  const int hi = l >> 5;
  const int e32 = l & 31;
  // LDS frag fetch: frag f of table at ushort-offset base -> 16B/lane, lane-linear
  auto LF = [&](int base, int f) {
    return *(const s16x8*)(wlds + base + f * 512 + l * 8);
  };

  int wid = blockIdx.x * 8 + wv;
  int nwv = gridDim.x * 8;
  const int NB = (MODE == 0) ? (NE / 32) : (NN / 32);
  const f32x16 z16 = {0.f, 0.f, 0.f, 0.f, 0.f, 0.f, 0.f, 0.f,
                      0.f, 0.f, 0.f, 0.f, 0.f, 0.f, 0.f, 0.f};

  // gather: lane = (edge e32, half hi). hi0 = sender/node, hi1 = receiver/pooled.
  float g0 = 0, g1 = 0, g2 = 0, g3 = 0, g4 = 0;
  auto PREF = [&](int bb) {
    if (bb < NB) {
      int e = (bb << 5) + e32;
      if (MODE == 0) {
        int idx = eidx[hi * NE + e];
        const float* np_ = nodes + idx * 5;
        g0 = np_[0]; g1 = np_[1]; g2 = np_[2]; g3 = np_[3]; g4 = np_[4];
      } else {
        if (hi == 0) {
          const float* np_ = nodes + e * 5;
          g0 = np_[0]; g1 = np_[1]; g2 = np_[2]; g3 = np_[3]; g4 = np_[4];
        } else {
          unsigned long long pl = pooled[e];
          int x32 = (int)(uint)pl;
          int y32 = (int)(pl >> 32) + (x32 < 0 ? 1 : 0);
          g0 = (float)x32 * (1.f / PSCALE);
          g1 = (float)y32 * (1.f / PSCALE);
        }
      }
    }
  };
  PREF(wid);

#pragma unroll 1
  for (int b = wid; b < NB; b += nwv) {
    const int rbase = b << 5;
    int rc = 0;
    if (MODE == 0) rc = eidx[NE + rbase + e32];
    // build the single L0 B-fragment
    s16x8 xf;
    {
      u32x4 f = {0u, 0u, 0u, 0u};
      if (MODE == 0) {
        f[0] = cvtpk(g0, g1); f[1] = cvtpk(g2, g3);
        f[2] = cvtpk(g4, hi ? 1.0f : 0.0f);          // bias rides k13 (hi=1,j=5)
      } else {
        if (hi == 0) { f[0] = cvtpk(g0, g1); f[1] = cvtpk(g2, g3); f[2] = cvtpk(g4, 0.f); }
        else         { f[0] = cvtpk(g0, g1); f[1] = cvtpk(1.0f, 0.f); }  // bias k10
      }
      xf = __builtin_bit_cast(s16x8, f);
    }
    PREF(b + nwv);

    // prefetch W0 (4 frags) + L1 mt=0 (8 frags) before any MFMA
    s16x8 w0f0 = LF(0, 0), w0f1 = LF(0, 1), w0f2 = LF(0, 2), w0f3 = LF(0, 3);
    s16x8 wf[2][8];
#pragma unroll
    for (int s = 0; s < 8; s++) wf[0][s] = LF(2048, s * 4);

    // L0: 4 MFMA (bias folded into W0)
    u32x4 phA[4][2];
    {
      f32x16 a;
      a = mfma32(w0f0, xf, z16); phA[0][0] = packg(a, 0); phA[0][1] = packg(a, 1);
      a = mfma32(w0f1, xf, z16); phA[1][0] = packg(a, 0); phA[1][1] = packg(a, 1);
      a = mfma32(w0f2, xf, z16); phA[2][0] = packg(a, 0); phA[2][1] = packg(a, 1);
      a = mfma32(w0f3, xf, z16); phA[3][0] = packg(a, 0); phA[3][1] = packg(a, 1);
    }
    // L1: stream 32 frags, double-buffered by output tile; mt=3 preloads L2 mt=0
    u32x4 phB[4][2];
#pragma unroll
    for (int mt = 0; mt < 4; mt++) {
      if (mt < 3) {
#pragma unroll
        for (int s = 0; s < 8; s++) wf[(mt + 1) & 1][s] = LF(2048, s * 4 + mt + 1);
      } else {
#pragma unroll
        for (int s = 0; s < 8; s++) wf[(mt + 1) & 1][s] = LF(18432, s * 4);
      }
      f32x16 a = loadbias(bias1, mt, hi);
#pragma unroll
      for (int s = 0; s < 8; s++)
        a = mfma32(wf[mt & 1][s], __builtin_bit_cast(s16x8, phA[s >> 1][s & 1]), a);
      phB[mt][0] = packg(a, 0);
      phB[mt][1] = packg(a, 1);
    }
    // L2: same stream; mt=3 preloads W3
    u32x4 phC[4][2];
#pragma unroll
    for (int mt = 0; mt < 4; mt++) {
      if (mt < 3) {
#pragma unroll
        for (int s = 0; s < 8; s++) wf[(mt + 1) & 1][s] = LF(18432, s * 4 + mt + 1);
      } else {
#pragma unroll
        for (int s = 0; s < 8; s++) wf[(mt + 1) & 1][s] = LF(34816, s);
      }
      f32x16 a = loadbias(bias2, mt, hi);
#pragma unroll
      for (int s = 0; s < 8; s++)
        a = mfma32(wf[mt & 1][s], __builtin_bit_cast(s16x8, phB[s >> 1][s & 1]), a);
      phC[mt][0] = packg(a, 0);
      phC[mt][1] = packg(a, 1);
    }
    // head: 8 MFMA chain; W3 frags already in wf[0]
    f32x16 a = mfma32(wf[0][0], __builtin_bit_cast(s16x8, phC[0][0]), z16);
#pragma unroll
    for (int s = 1; s < 8; s++)
      a = mfma32(wf[0][s], __builtin_bit_cast(s16x8, phC[s >> 1][s & 1]), a);

    int e = rbase + e32;
    if (hi == 0) {
      float mv0 = a[0] + bias3[0], mv1 = a[1] + bias3[1];
      if (MODE == 0) {
        // ONE exact fixed-point u64 atomic per edge (r14, verified)
        int ix = (int)rintf(mv0 * PSCALE);
        int iy = (int)rintf(mv1 * PSCALE);
        long long ad = (((long long)iy) << 32) + (long long)ix;
        atomicAdd(&pooled[rc], (unsigned long long)ad);
      } else {
        out[e * 5 + 2] = nodes[e * 5 + 2] + mv0;
        out[e * 5 + 3] = nodes[e * 5 + 3] + mv1;
      }
    } else if (MODE == 1) {
      out[e * 5 + 0] = nodes[e * 5 + 0];
      out[e * 5 + 1] = nodes[e * 5 + 1];
      out[e * 5 + 4] = nodes[e * 5 + 4];
    }
  }
}

extern "C" void kernel_launch(void* const* d_in, const int* in_sizes, int n_in,
                              void* d_out, int out_size, void* d_ws, size_t ws_size,
                              hipStream_t stream) {
  const float* nodes = (const float*)d_in[0];
  const int* eidx = (const int*)d_in[1];
  const float* Wm0 = (const float*)d_in[2];  const float* bm0 = (const float*)d_in[3];
  const float* Wm1 = (const float*)d_in[4];  const float* bm1 = (const float*)d_in[5];
  const float* Wm2 = (const float*)d_in[6];  const float* bm2 = (const float*)d_in[7];
  const float* Wm3 = (const float*)d_in[8];  const float* bm3 = (const float*)d_in[9];
  const float* Wu0 = (const float*)d_in[10]; const float* bu0 = (const float*)d_in[11];
  const float* Wu1 = (const float*)d_in[12]; const float* bu1 = (const float*)d_in[13];
  const float* Wu2 = (const float*)d_in[14]; const float* bu2 = (const float*)d_in[15];
  const float* Wu3 = (const float*)d_in[16]; const float* bu3 = (const float*)d_in[17];

  unsigned long long* pooled = (unsigned long long*)d_ws;  // NN u64 = 800000 B
  ushort* wbuf = (ushort*)((char*)d_ws + 800000);          // prearranged bf16 frags

  hipMemsetAsync(pooled, 0, NN * 8, stream);
  prep_weights<<<8, 256, 0, stream>>>(Wm0, Wm1, Wm2, Wm3, Wu0, Wu1, Wu2, Wu3,
                                      bm0, bu0, wbuf);

  gnn_kernel<0><<<256, 512, 0, stream>>>(nodes, eidx, pooled, wbuf,
                                         bm1, bm2, bm3, nullptr);
  gnn_kernel<1><<<256, 512, 0, stream>>>(nodes, nullptr, pooled, wbuf + 38912,
                                         bu1, bu2, bu3, (float*)d_out);
}